// Round 6
// baseline (167.745 us; speedup 1.0000x reference)
//
#include <hip/hip_runtime.h>
#include <stdint.h>

#define AS1 __attribute__((address_space(1)))
#define AS3 __attribute__((address_space(3)))

typedef short short8 __attribute__((ext_vector_type(8)));
typedef unsigned short ushort8 __attribute__((ext_vector_type(8)));
typedef __bf16 bf16x8 __attribute__((ext_vector_type(8)));
typedef float floatx4 __attribute__((ext_vector_type(4)));

__device__ __forceinline__ floatx4 mfma16(short8 a, short8 b, floatx4 c) {
  return __builtin_amdgcn_mfma_f32_16x16x32_bf16(
      __builtin_bit_cast(bf16x8, a), __builtin_bit_cast(bf16x8, b), c, 0, 0, 0);
}

__device__ __forceinline__ unsigned short f2bf(float f) {
  uint32_t u = __builtin_bit_cast(uint32_t, f);
  u = (u + 0x7FFFu + ((u >> 16) & 1u)) >> 16;
  return (unsigned short)u;
}

// packed f32x2 -> bf16x2, 1 VALU instr for 2 values
__device__ __forceinline__ uint32_t cvt_pk_bf16(float a, float b) {
  uint32_t d;
  asm("v_cvt_pk_bf16_f32 %0, %1, %2" : "=v"(d) : "v"(a), "v"(b));
  return d;
}

// ---------------------------------------------------------------------------
// Staging-tiled layout (validated on HW in rounds 4/5): matrix stored as 1-KB
// blocks, block blk = ((row/128)*32 + col/32)*8 + (row/16)%8, content
// lane-linear: elem (lane*8+e) = M[16rowgrp + lane%16][colgrp8(lane/16)+e].
// Every gemm global_load_lds chunk = one contiguous 1-KB lane-linear read.
// ---------------------------------------------------------------------------
__device__ __forceinline__ size_t tiled_off(int row, int col) {
  int rt = row >> 7, c8 = (row >> 4) & 7, rr = row & 15;
  int t = col >> 5, lh = (col >> 3) & 3, e = col & 7;
  return ((size_t)((rt * 32 + t) * 8 + c8) << 9) + (lh * 16 + rr) * 8 + e;
}

// ---------------------------------------------------------------------------
// Convert/pack v3: one WAVE per 1-KB output block (unchanged from round 5).
// ---------------------------------------------------------------------------
__global__ __launch_bounds__(256) void convert_pack(
    const float* __restrict__ x, const float* __restrict__ wq,
    const float* __restrict__ wk, const float* __restrict__ wv,
    const float* __restrict__ wo, unsigned short* __restrict__ xb,
    unsigned short* __restrict__ wqkvb, unsigned short* __restrict__ wob) {
  const int lane = threadIdx.x & 63;
  const int wid = threadIdx.x >> 6;
  const int b = blockIdx.x * 4 + wid;  // 0..16383
  const int lrow = lane & 15, lkg = lane >> 4;
  const float* src;
  unsigned short* dst;
  if (b < 8192) {  // x: 4096x1024
    int rt = b >> 8, wi = b & 255, t = wi >> 3, c8 = wi & 7;
    int row = rt * 128 + c8 * 16 + lrow;
    src = x + (size_t)row * 1024 + t * 32 + lkg * 8;
    dst = xb + ((size_t)b << 9) + lane * 8;
  } else if (b < 14336) {  // Wq|Wk|Wv -> Wqkv rows 0..3071
    int jb = b - 8192;
    int rt = jb >> 8, wi = jb & 255, t = wi >> 3, c8 = wi & 7;
    int row = rt * 128 + c8 * 16 + lrow;  // 0..3071
    int r = row >> 10, srow = row & 1023;
    const float* m = (r == 0) ? wq : (r == 1) ? wk : wv;
    src = m + (size_t)srow * 1024 + t * 32 + lkg * 8;
    dst = wqkvb + ((size_t)jb << 9) + lane * 8;
  } else {  // Wo: 1024x1024
    int jb = b - 14336;
    int rt = jb >> 8, wi = jb & 255, t = wi >> 3, c8 = wi & 7;
    int row = rt * 128 + c8 * 16 + lrow;
    src = wo + (size_t)row * 1024 + t * 32 + lkg * 8;
    dst = wob + ((size_t)jb << 9) + lane * 8;
  }
  float4 a = *(const float4*)src;
  float4 c = *(const float4*)(src + 4);
  ushort8 o;
  o[0] = f2bf(a.x); o[1] = f2bf(a.y); o[2] = f2bf(a.z); o[3] = f2bf(a.w);
  o[4] = f2bf(c.x); o[5] = f2bf(c.y); o[6] = f2bf(c.z); o[7] = f2bf(c.w);
  *(ushort8*)dst = o;
}

// ---------------------------------------------------------------------------
// GEMM 256x256 tile (QKV projection): C[M][N] = A[M][K] @ B[N][K]^T.
// Round-6: 128->256 tile to HALVE L2 panel traffic (gemm_bt measured
// ~38.8 B/cyc/CU staging ~= 65% of L2 BW at 128^2 -> BW-bound; 256^2 halves
// bytes/FLOP). Same proven skeleton: 3 x 32KB tiled-chunk staging buffers,
// 4 global_load_lds/wave/stage, counted vmcnt(4), raw s_barrier, depth-2.
// 512 thr = 8 waves (2M x 4N, 128x64 out each). Grid (16,12)=192 WGs, 1/CU;
// bijective XCD map: 4 M-tiles x 6 N-tiles per XCD (3.5MB panels < 4MB L2).
// ---------------------------------------------------------------------------
template <typename OutT>
__global__ __launch_bounds__(512) void gemm_bt(const unsigned short* __restrict__ A,
                                               const unsigned short* __restrict__ Bm,
                                               OutT* __restrict__ C, int N, int K) {
  __shared__ unsigned short lds[3][32 * 512];  // 3 x 32 KB (BK=32, 256+256 rows)
  const int tid = threadIdx.x;
  const int lane = tid & 63;
  const int w = tid >> 6;        // 0..7
  const int wrm = w >> 2;        // 0..1  (M wave row)
  const int wcn = w & 3;         // 0..3  (N wave col)
  const int lrow = lane & 15;

  // XCD-compact map for grid (16,12)=192: lid%8 = XCD, 24 WGs per XCD.
  const int lid = blockIdx.y * gridDim.x + blockIdx.x;
  const int xcd = lid & 7;
  const int idx = lid >> 3;                  // 0..23
  const int mt = (xcd & 3) * 4 + (idx & 3);  // 0..15
  const int nt = (xcd >> 2) * 6 + (idx >> 2);// 0..11
  const int tm = mt * 256, tn = nt * 256;

  floatx4 acc[8][4];
#pragma unroll
  for (int i = 0; i < 8; ++i)
#pragma unroll
    for (int j = 0; j < 4; ++j) acc[i][j] = floatx4{0.f, 0.f, 0.f, 0.f};

  // Stage one BK=32 K-slice: A rows tm..tm+255 (chunks 0-15), B rows
  // tn..tn+255 (chunks 16-31). Each chunk = contiguous 1-KB tiled block.
  auto stage = [&](unsigned short* buf, int t) {
#pragma unroll
    for (int c = w * 4; c < w * 4 + 4; ++c) {
      const unsigned short* g;
      if (c < 16) {
        int rt = 2 * mt + (c >> 3);
        g = A + ((size_t)((rt * 32 + t) * 8 + (c & 7)) << 9) + lane * 8;
      } else {
        int cc = c - 16;
        int rt = 2 * nt + (cc >> 3);
        g = Bm + ((size_t)((rt * 32 + t) * 8 + (cc & 7)) << 9) + lane * 8;
      }
      __builtin_amdgcn_global_load_lds((const AS1 uint32_t*)g,
                                       (AS3 uint32_t*)(buf + c * 512), 16, 0, 0);
    }
  };

  auto compute = [&](const unsigned short* L) {
    short8 af[8], bf[4];
#pragma unroll
    for (int i = 0; i < 8; ++i)
      af[i] = *(const short8*)&L[(wrm * 8 + i) * 512 + lane * 8];
#pragma unroll
    for (int j = 0; j < 4; ++j)
      bf[j] = *(const short8*)&L[(16 + wcn * 4 + j) * 512 + lane * 8];
#pragma unroll
    for (int i = 0; i < 8; ++i)
#pragma unroll
      for (int j = 0; j < 4; ++j) acc[i][j] = mfma16(af[i], bf[j], acc[i][j]);
  };

  stage(lds[0], 0);
  stage(lds[1], 1);

  const int T = K >> 5;  // 32
  int bt = 0;            // t % 3
  for (int t = 0; t < T - 1; ++t) {
    // wait for stage t (own wave's oldest 4); leave stage t+1's 4 in flight
    asm volatile("s_waitcnt vmcnt(4)" ::: "memory");
    __builtin_amdgcn_sched_barrier(0);
    __builtin_amdgcn_s_barrier();  // cross-wave: all chunks of stage t in LDS
    __builtin_amdgcn_sched_barrier(0);
    if (t + 2 < T) {
      int b2 = (bt + 2 >= 3) ? bt - 1 : bt + 2;
      stage(lds[b2], t + 2);  // issue early: lands under compute
    }
    compute(lds[bt]);
    bt = (bt + 1 == 3) ? 0 : bt + 1;
  }
  // peeled final iteration: only stage T-1 outstanding
  asm volatile("s_waitcnt vmcnt(0)" ::: "memory");
  __builtin_amdgcn_sched_barrier(0);
  __builtin_amdgcn_s_barrier();
  __builtin_amdgcn_sched_barrier(0);
  compute(lds[bt]);

  const int r0 = (lane >> 4) * 4;
#pragma unroll
  for (int i = 0; i < 8; ++i)
#pragma unroll
    for (int j = 0; j < 4; ++j)
#pragma unroll
      for (int r = 0; r < 4; ++r) {
        int row = tm + wrm * 128 + i * 16 + r0 + r;
        int col = tn + wcn * 64 + j * 16 + lrow;
        float v = acc[i][j][r];
        if constexpr (sizeof(OutT) == 2)
          C[(size_t)row * N + col] = f2bf(v);
        else
          C[(size_t)row * N + col] = v;
      }
}

// ---------------------------------------------------------------------------
// GEMM 64x128 tile (output projection). Unchanged from round 5 (both sides
// staging-tiled; counted-vmcnt 3-buffer pipeline).
// ---------------------------------------------------------------------------
__global__ __launch_bounds__(256) void gemm64(const unsigned short* __restrict__ A,
                                              const unsigned short* __restrict__ Bm,
                                              float* __restrict__ C, int N, int K) {
  __shared__ unsigned short lds[3][12 * 512];  // A: chunks 0-3, B: 4-11
  const int tid = threadIdx.x;
  const int lane = tid & 63;
  const int w = tid >> 6;
  const int wr = w >> 1, wc = w & 1;

  const int lid = blockIdx.y * gridDim.x + blockIdx.x;
  const int xcd = lid & 7;
  const int wgid = xcd * 64 + (lid >> 3);  // 0..511, contiguous per XCD
  const int s = wgid >> 5, w5 = wgid & 31; // supertile 0..15, within 0..31
  const int mt = (s & 3) * 16 + (w5 & 15); // 0..63
  const int nt = (s >> 2) * 2 + (w5 >> 4); // 0..7
  const int tm = mt * 64, tn = nt * 128;
  const int lrow = lane & 15;

  floatx4 acc[2][4];
#pragma unroll
  for (int i = 0; i < 2; ++i)
#pragma unroll
    for (int j = 0; j < 4; ++j) acc[i][j] = floatx4{0.f, 0.f, 0.f, 0.f};

  // A tile rows tm..tm+63: 128-row tile rt = mt>>1, chunks (mt&1)*4 + c.
  auto stage = [&](unsigned short* buf, int t) {
#pragma unroll
    for (int c = w * 3; c < w * 3 + 3; ++c) {
      const unsigned short* g;
      if (c < 4)
        g = A + ((size_t)(((mt >> 1) * 32 + t) * 8 + ((mt & 1) * 4 + c)) << 9) + lane * 8;
      else
        g = Bm + ((size_t)((nt * 32 + t) * 8 + (c - 4)) << 9) + lane * 8;
      __builtin_amdgcn_global_load_lds((const AS1 uint32_t*)g,
                                       (AS3 uint32_t*)(buf + c * 512), 16, 0, 0);
    }
  };

  auto compute = [&](const unsigned short* L) {
    short8 af[2], bf[4];
#pragma unroll
    for (int i = 0; i < 2; ++i)
      af[i] = *(const short8*)&L[(wr * 2 + i) * 512 + lane * 8];
#pragma unroll
    for (int j = 0; j < 4; ++j)
      bf[j] = *(const short8*)&L[(4 + wc * 4 + j) * 512 + lane * 8];
#pragma unroll
    for (int i = 0; i < 2; ++i)
#pragma unroll
      for (int j = 0; j < 4; ++j) acc[i][j] = mfma16(af[i], bf[j], acc[i][j]);
  };

  stage(lds[0], 0);
  stage(lds[1], 1);

  const int T = K >> 5;  // 32
  int bt = 0;
  for (int t = 0; t < T - 1; ++t) {
    asm volatile("s_waitcnt vmcnt(3)" ::: "memory");
    __builtin_amdgcn_sched_barrier(0);
    __builtin_amdgcn_s_barrier();
    __builtin_amdgcn_sched_barrier(0);
    if (t + 2 < T) {
      int b2 = (bt + 2 >= 3) ? bt - 1 : bt + 2;
      stage(lds[b2], t + 2);
    }
    compute(lds[bt]);
    bt = (bt + 1 == 3) ? 0 : bt + 1;
  }
  asm volatile("s_waitcnt vmcnt(0)" ::: "memory");
  __builtin_amdgcn_sched_barrier(0);
  __builtin_amdgcn_s_barrier();
  __builtin_amdgcn_sched_barrier(0);
  compute(lds[bt]);

  const int r0 = (lane >> 4) * 4;
#pragma unroll
  for (int i = 0; i < 2; ++i)
#pragma unroll
    for (int j = 0; j < 4; ++j)
#pragma unroll
      for (int r = 0; r < 4; ++r) {
        int row = tm + (wr * 2 + i) * 16 + r0 + r;
        int col = tn + (wc * 4 + j) * 16 + lrow;
        C[(size_t)row * N + col] = acc[i][j][r];
      }
}

// ---------------------------------------------------------------------------
// Flash attention, S^T orientation, 128 q/WG, 128-key blocks + 16-key sink.
// (unchanged from round 5; epilogue writes AO staging-tiled for gemm64)
// ---------------------------------------------------------------------------
__global__ __launch_bounds__(256) void attn_kernel(const unsigned short* __restrict__ qkv,
                                                   unsigned short* __restrict__ aout) {
  __shared__ unsigned short Klds[2][16 * 512];  // 2 x 16KB A-frag chunks
  __shared__ unsigned short VT[64 * 136];       // V^T [d][key], stride 136
  __shared__ unsigned short PT[4][16 * 136];    // per-wave P^T [q][key]

  const int tid = threadIdx.x;
  const int lane = tid & 63;
  const int w = tid >> 6;
  const int lrow = lane & 15;
  const int lkg = lane >> 4;

  const int i = blockIdx.x;
  const int half = i >> 8;
  const int j = (i >> 3) & 31;
  const int h = 2 * (i & 7) + half;
  const int qb = half ? (31 - j) : j;
  const int q0 = qb * 128;

  short8 qf[2][2];
#pragma unroll
  for (int qt = 0; qt < 2; ++qt)
#pragma unroll
    for (int ks = 0; ks < 2; ++ks)
      qf[qt][ks] = *(const short8*)&qkv[(size_t)(q0 + qt * 64 + w * 16 + lrow) * 3072 +
                                        h * 64 + ks * 32 + lkg * 8];

  float m_i[2], l_i[2];
  floatx4 o[4][2];
#pragma unroll
  for (int qt = 0; qt < 2; ++qt) {
    m_i[qt] = -1e30f;
    l_i[qt] = 0.f;
#pragma unroll
    for (int nt = 0; nt < 4; ++nt) o[nt][qt] = floatx4{0.f, 0.f, 0.f, 0.f};
  }

  const float scale2 = 0.125f * 1.44269504088896f;  // 1/sqrt(64) * log2(e)

  // ---- prologue: stage sink K/V; prefetch window block 0 ----
  if (w < 2) {  // sink K chunks 0,1 into Klds[0]
    const unsigned short* g = &qkv[(size_t)lrow * 3072 + 1024 + h * 64 + w * 32 + lkg * 8];
    __builtin_amdgcn_global_load_lds((const AS1 uint32_t*)g,
                                     (AS3 uint32_t*)(&Klds[0][w * 512]), 16, 0, 0);
  }
  {  // sink V^T keys 0..31 (PV spans 0..31; P=0 for 16..31)
    if (lane < 16) {
      const unsigned short* g0 = &qkv[(size_t)(2 * lane) * 3072 + 2048 + h * 64 + w * 16];
      ushort8 a0 = *(const ushort8*)g0;
      ushort8 a1 = *(const ushort8*)(g0 + 8);
      ushort8 b0 = *(const ushort8*)(g0 + 3072);
      ushort8 b1 = *(const ushort8*)(g0 + 3080);
      uint32_t* vt = (uint32_t*)VT;
#pragma unroll
      for (int dd = 0; dd < 8; ++dd) {
        vt[(w * 16 + dd) * 68 + lane] = (uint32_t)a0[dd] | ((uint32_t)b0[dd] << 16);
        vt[(w * 16 + 8 + dd) * 68 + lane] = (uint32_t)a1[dd] | ((uint32_t)b1[dd] << 16);
      }
    }
  }
  const int kb0 = (q0 - 511 < 16) ? 16 : (q0 - 511);
  // prefetch window block 0: K -> Klds[1], V -> registers
#pragma unroll
  for (int c = 0; c < 4; ++c) {
    int ch = w * 4 + c;
    int kt = ch >> 1, ks = ch & 1;
    const unsigned short* g =
        &qkv[(size_t)(kb0 + kt * 16 + lrow) * 3072 + 1024 + h * 64 + ks * 32 + lkg * 8];
    __builtin_amdgcn_global_load_lds((const AS1 uint32_t*)g,
                                     (AS3 uint32_t*)(&Klds[1][ch * 512]), 16, 0, 0);
  }
  ushort8 va0, va1, vb0, vb1;
  {
    const unsigned short* g0 = &qkv[(size_t)(kb0 + 2 * lane) * 3072 + 2048 + h * 64 + w * 16];
    va0 = *(const ushort8*)g0;
    va1 = *(const ushort8*)(g0 + 8);
    vb0 = *(const ushort8*)(g0 + 3072);
    vb1 = *(const ushort8*)(g0 + 3080);
  }
  __syncthreads();

  // ---- sink compute (keys 0..15; PV over 0..31 with P=0 padding) ----
#pragma unroll
  for (int qt = 0; qt < 2; ++qt) {
    const int qq = q0 + qt * 64 + w * 16 + lrow;
    floatx4 s0 = floatx4{0.f, 0.f, 0.f, 0.f};
#pragma unroll
    for (int ks = 0; ks < 2; ++ks) {
      short8 kf = *(const short8*)&Klds[0][ks * 512 + lane * 8];
      s0 = mfma16(kf, qf[qt][ks], s0);
    }
    float mx = -1e30f;
    float sv[4];
#pragma unroll
    for (int r = 0; r < 4; ++r) {
      int key = lkg * 4 + r;
      bool vis = (key <= qq) && ((key < 4) || (key >= qq - 511));
      sv[r] = vis ? s0[r] * scale2 : -1e30f;
      mx = fmaxf(mx, sv[r]);
    }
    mx = fmaxf(mx, __shfl_xor(mx, 16));
    mx = fmaxf(mx, __shfl_xor(mx, 32));
    m_i[qt] = mx;  // key 0 always visible -> finite
    float p0 = exp2f(sv[0] - mx), p1 = exp2f(sv[1] - mx);
    float p2 = exp2f(sv[2] - mx), p3 = exp2f(sv[3] - mx);
    float ps = (p0 + p1) + (p2 + p3);
    *(uint2*)&PT[w][lrow * 136 + lkg * 4] = uint2{cvt_pk_bf16(p0, p1), cvt_pk_bf16(p2, p3)};
    *(uint2*)&PT[w][lrow * 136 + 16 + lkg * 4] = uint2{0u, 0u};  // keys 16..31 = 0
    ps += __shfl_xor(ps, 16);
    ps += __shfl_xor(ps, 32);
    l_i[qt] = ps;
    short8 pf = *(const short8*)&PT[w][lrow * 136 + lkg * 8];
#pragma unroll
    for (int nt = 0; nt < 4; ++nt) {
      short8 vf = *(const short8*)&VT[(nt * 16 + lrow) * 136 + lkg * 8];
      o[nt][qt] = mfma16(vf, pf, o[nt][qt]);
    }
  }

  // ---- window blocks of 128 keys (pipelined) ----
  int nbuf = 1;
  for (int kb = kb0; kb < q0 + 128; kb += 128) {
    const bool hasnext = (kb + 128 < q0 + 128);
    __syncthreads();  // prev readers of VT done; this block's K/V prefetch drained (landed)
    {  // write V^T for this block from prefetched registers
      uint32_t* vt = (uint32_t*)VT;
#pragma unroll
      for (int dd = 0; dd < 8; ++dd) {
        vt[(w * 16 + dd) * 68 + lane] = (uint32_t)va0[dd] | ((uint32_t)vb0[dd] << 16);
        vt[(w * 16 + 8 + dd) * 68 + lane] = (uint32_t)va1[dd] | ((uint32_t)vb1[dd] << 16);
      }
    }
    __syncthreads();  // VT visible

    // issue prefetches for block n+1 (after the barrier so the drain above
    // never waits on them; they land during this block's compute)
    if (hasnext) {
      const int kn = kb + 128;
#pragma unroll
      for (int c = 0; c < 4; ++c) {
        int ch = w * 4 + c;
        int kt = ch >> 1, ks = ch & 1;
        const unsigned short* g =
            &qkv[(size_t)(kn + kt * 16 + lrow) * 3072 + 1024 + h * 64 + ks * 32 + lkg * 8];
        __builtin_amdgcn_global_load_lds((const AS1 uint32_t*)g,
                                         (AS3 uint32_t*)(&Klds[1 - nbuf][ch * 512]), 16, 0, 0);
      }
      const unsigned short* g0 = &qkv[(size_t)(kn + 2 * lane) * 3072 + 2048 + h * 64 + w * 16];
      va0 = *(const ushort8*)g0;
      va1 = *(const ushort8*)(g0 + 8);
      vb0 = *(const ushort8*)(g0 + 3072);
      vb1 = *(const ushort8*)(g0 + 3080);
    }

#pragma unroll
    for (int qt = 0; qt < 2; ++qt) {
      const int qaT = q0 + qt * 64 + w * 16;  // wave-uniform
      const int qq = qaT + lrow;
      floatx4 s[8];
#pragma unroll
      for (int ct = 0; ct < 8; ++ct) {
        s[ct] = floatx4{0.f, 0.f, 0.f, 0.f};
#pragma unroll
        for (int ks = 0; ks < 2; ++ks) {
          short8 kf = *(const short8*)&Klds[nbuf][(ct * 2 + ks) * 512 + lane * 8];
          s[ct] = mfma16(kf, qf[qt][ks], s[ct]);
        }
      }
      const bool full = (kb + 127 <= qaT) && (kb >= qaT + 15 - 511);
      float mx = -1e30f;
#pragma unroll
      for (int ct = 0; ct < 8; ++ct)
#pragma unroll
        for (int r = 0; r < 4; ++r) {
          float val = s[ct][r] * scale2;
          if (!full) {
            int key = kb + ct * 16 + lkg * 4 + r;
            bool vis = (key <= qq) && (key >= qq - 511);
            val = vis ? val : -1e30f;
          }
          s[ct][r] = val;
          mx = fmaxf(mx, val);
        }
      mx = fmaxf(mx, __shfl_xor(mx, 16));
      mx = fmaxf(mx, __shfl_xor(mx, 32));
      float nm = fmaxf(m_i[qt], mx);
      float alpha = exp2f(m_i[qt] - nm);
      m_i[qt] = nm;

      float ps = 0.f;
#pragma unroll
      for (int ct = 0; ct < 8; ++ct) {
        float p0 = exp2f(s[ct][0] - nm), p1 = exp2f(s[ct][1] - nm);
        float p2 = exp2f(s[ct][2] - nm), p3 = exp2f(s[ct][3] - nm);
        ps += (p0 + p1) + (p2 + p3);
        *(uint2*)&PT[w][lrow * 136 + ct * 16 + lkg * 4] =
            uint2{cvt_pk_bf16(p0, p1), cvt_pk_bf16(p2, p3)};
      }
      ps += __shfl_xor(ps, 16);
      ps += __shfl_xor(ps, 32);
      l_i[qt] = l_i[qt] * alpha + ps;

#pragma unroll
      for (int nt = 0; nt < 4; ++nt)
#pragma unroll
        for (int r = 0; r < 4; ++r) o[nt][qt][r] *= alpha;

#pragma unroll
      for (int kk = 0; kk < 4; ++kk) {
        short8 pf = *(const short8*)&PT[w][lrow * 136 + kk * 32 + lkg * 8];
#pragma unroll
        for (int nt = 0; nt < 4; ++nt) {
          short8 vf = *(const short8*)&VT[(nt * 16 + lrow) * 136 + kk * 32 + lkg * 8];
          o[nt][qt] = mfma16(vf, pf, o[nt][qt]);
        }
      }
    }
    nbuf ^= 1;
  }

  // ---- epilogue: write AO in staging-tiled layout for gemm64 ----
#pragma unroll
  for (int qt = 0; qt < 2; ++qt) {
    const int qq = q0 + qt * 64 + w * 16 + lrow;
    const float inv = 1.0f / l_i[qt];
#pragma unroll
    for (int nt = 0; nt < 4; ++nt) {
      floatx4 ov = o[nt][qt];
      uint32_t lo = cvt_pk_bf16(ov[0] * inv, ov[1] * inv);
      uint32_t hi = cvt_pk_bf16(ov[2] * inv, ov[3] * inv);
      int col = h * 64 + nt * 16 + lkg * 4;
      *(uint2*)&aout[tiled_off(qq, col)] = uint2{lo, hi};
    }
  }
}

// ---------------------------------------------------------------------------
extern "C" void kernel_launch(void* const* d_in, const int* in_sizes, int n_in,
                              void* d_out, int out_size, void* d_ws, size_t ws_size,
                              hipStream_t stream) {
  const float* x = (const float*)d_in[0];
  const float* wq = (const float*)d_in[1];
  const float* wk = (const float*)d_in[2];
  const float* wv = (const float*)d_in[3];
  const float* wo = (const float*)d_in[4];

  char* ws = (char*)d_ws;
  unsigned short* Xb = (unsigned short*)(ws);                 // 8 MB (tiled)
  unsigned short* Wqkv = (unsigned short*)(ws + (8u << 20));  // 6 MB (tiled)
  unsigned short* Wob = (unsigned short*)(ws + (14u << 20));  // 2 MB (tiled)
  unsigned short* QKV = (unsigned short*)(ws + (16u << 20));  // 24 MB
  unsigned short* AO = (unsigned short*)(ws + (40u << 20));   // 8 MB (tiled)

  convert_pack<<<4096, 256, 0, stream>>>(x, wq, wk, wv, wo, Xb, Wqkv, Wob);
  gemm_bt<unsigned short><<<dim3(16, 12), 512, 0, stream>>>(Xb, Wqkv, QKV, 3072, 1024);
  attn_kernel<<<512, 256, 0, stream>>>(QKV, AO);
  gemm64<<<dim3(64, 8), 256, 0, stream>>>(AO, Wob, (float*)d_out, 1024, 1024);
}

// Round 7
// 165.896 us; speedup vs baseline: 1.0111x; 1.0111x over previous
//
#include <hip/hip_runtime.h>
#include <stdint.h>

#define AS1 __attribute__((address_space(1)))
#define AS3 __attribute__((address_space(3)))

typedef short short8 __attribute__((ext_vector_type(8)));
typedef unsigned short ushort8 __attribute__((ext_vector_type(8)));
typedef __bf16 bf16x8 __attribute__((ext_vector_type(8)));
typedef float floatx4 __attribute__((ext_vector_type(4)));

__device__ __forceinline__ floatx4 mfma16(short8 a, short8 b, floatx4 c) {
  return __builtin_amdgcn_mfma_f32_16x16x32_bf16(
      __builtin_bit_cast(bf16x8, a), __builtin_bit_cast(bf16x8, b), c, 0, 0, 0);
}

__device__ __forceinline__ unsigned short f2bf(float f) {
  uint32_t u = __builtin_bit_cast(uint32_t, f);
  u = (u + 0x7FFFu + ((u >> 16) & 1u)) >> 16;
  return (unsigned short)u;
}

// packed f32x2 -> bf16x2, 1 VALU instr for 2 values
__device__ __forceinline__ uint32_t cvt_pk_bf16(float a, float b) {
  uint32_t d;
  asm("v_cvt_pk_bf16_f32 %0, %1, %2" : "=v"(d) : "v"(a), "v"(b));
  return d;
}

// ---------------------------------------------------------------------------
// Staging-tiled layout (HW-validated R4/R5): 1-KB lane-linear blocks.
// ---------------------------------------------------------------------------
__device__ __forceinline__ size_t tiled_off(int row, int col) {
  int rt = row >> 7, c8 = (row >> 4) & 7, rr = row & 15;
  int t = col >> 5, lh = (col >> 3) & 3, e = col & 7;
  return ((size_t)((rt * 32 + t) * 8 + c8) << 9) + (lh * 16 + rr) * 8 + e;
}

// Per-head chunk-tiled Q/K layout: chunk(16 rows x 32 dims) = contiguous 1KB,
// content lane-linear (lane -> row lane&15, dimgrp lane>>4). Element addr:
__device__ __forceinline__ size_t qk_off(int h, int row, int dd) {
  return ((size_t)((h * 256 + (row >> 4)) * 2 + (dd >> 5)) << 9) +
         ((((dd >> 3) & 3) * 16 + (row & 15)) << 3) + (dd & 7);
}

// ---------------------------------------------------------------------------
// Convert/pack v3: one WAVE per 1-KB output block (unchanged from round 5).
// ---------------------------------------------------------------------------
__global__ __launch_bounds__(256) void convert_pack(
    const float* __restrict__ x, const float* __restrict__ wq,
    const float* __restrict__ wk, const float* __restrict__ wv,
    const float* __restrict__ wo, unsigned short* __restrict__ xb,
    unsigned short* __restrict__ wqkvb, unsigned short* __restrict__ wob) {
  const int lane = threadIdx.x & 63;
  const int wid = threadIdx.x >> 6;
  const int b = blockIdx.x * 4 + wid;  // 0..16383
  const int lrow = lane & 15, lkg = lane >> 4;
  const float* src;
  unsigned short* dst;
  if (b < 8192) {  // x: 4096x1024
    int rt = b >> 8, wi = b & 255, t = wi >> 3, c8 = wi & 7;
    int row = rt * 128 + c8 * 16 + lrow;
    src = x + (size_t)row * 1024 + t * 32 + lkg * 8;
    dst = xb + ((size_t)b << 9) + lane * 8;
  } else if (b < 14336) {  // Wq|Wk|Wv -> Wqkv rows 0..3071
    int jb = b - 8192;
    int rt = jb >> 8, wi = jb & 255, t = wi >> 3, c8 = wi & 7;
    int row = rt * 128 + c8 * 16 + lrow;  // 0..3071
    int r = row >> 10, srow = row & 1023;
    const float* m = (r == 0) ? wq : (r == 1) ? wk : wv;
    src = m + (size_t)srow * 1024 + t * 32 + lkg * 8;
    dst = wqkvb + ((size_t)jb << 9) + lane * 8;
  } else {  // Wo: 1024x1024
    int jb = b - 14336;
    int rt = jb >> 8, wi = jb & 255, t = wi >> 3, c8 = wi & 7;
    int row = rt * 128 + c8 * 16 + lrow;
    src = wo + (size_t)row * 1024 + t * 32 + lkg * 8;
    dst = wob + ((size_t)jb << 9) + lane * 8;
  }
  float4 a = *(const float4*)src;
  float4 c = *(const float4*)(src + 4);
  ushort8 o;
  o[0] = f2bf(a.x); o[1] = f2bf(a.y); o[2] = f2bf(a.z); o[3] = f2bf(a.w);
  o[4] = f2bf(c.x); o[5] = f2bf(c.y); o[6] = f2bf(c.z); o[7] = f2bf(c.w);
  *(ushort8*)dst = o;
}

// ---------------------------------------------------------------------------
// GEMM 128x128 tile (QKV projection), R5-proven structure (reverted from the
// 256^2 regression: grid 192<256 CUs left 25% idle). Inputs staging-tiled;
// 3 x 16KB buffers, depth-2 counted-vmcnt pipeline, XCD-compact swizzle.
// Epilogue now writes attn-NATIVE layouts: Q,K chunk-tiled per head (so
// attn's global_load_lds chunks are contiguous 1-KB reads -- the same
// mechanism that fixed gemm staging in R4), V per-head row-major [h][S][64]
// (dense 128-B rows instead of 6-KB-strided).
// ---------------------------------------------------------------------------
__global__ __launch_bounds__(256) void gemm_qkv(const unsigned short* __restrict__ A,
                                                const unsigned short* __restrict__ Bm,
                                                unsigned short* __restrict__ Qb,
                                                unsigned short* __restrict__ Kb,
                                                unsigned short* __restrict__ Vh,
                                                int K) {
  __shared__ unsigned short lds[3][16 * 512];  // 3 x 16 KB (BK=32)
  const int tid = threadIdx.x;
  const int lane = tid & 63;
  const int w = tid >> 6;
  const int wr = w >> 1, wc = w & 1;

  // XCD-compact supertile swizzle for grid (32,24)=768 (bijective).
  const int lid = blockIdx.y * gridDim.x + blockIdx.x;
  const int xcd = lid & 7;
  const int wgid = xcd * 96 + (lid >> 3);  // 0..767, contiguous per XCD
  const int s = wgid >> 5, w5 = wgid & 31; // supertile 0..23, within 0..31
  const int mt = (s & 3) * 8 + (w5 & 7);   // 0..31
  const int nt = (s >> 2) * 4 + (w5 >> 3); // 0..23
  const int tm = mt * 128, tn = nt * 128;
  const int lrow = lane & 15;

  floatx4 acc[4][4];
#pragma unroll
  for (int i = 0; i < 4; ++i)
#pragma unroll
    for (int j = 0; j < 4; ++j) acc[i][j] = floatx4{0.f, 0.f, 0.f, 0.f};

  auto stage = [&](unsigned short* buf, int t) {
#pragma unroll
    for (int c = w * 4; c < w * 4 + 4; ++c) {
      const unsigned short* g;
      if (c < 8)
        g = A + ((size_t)((mt * 32 + t) * 8 + c) << 9) + lane * 8;
      else
        g = Bm + ((size_t)((nt * 32 + t) * 8 + (c - 8)) << 9) + lane * 8;
      __builtin_amdgcn_global_load_lds((const AS1 uint32_t*)g,
                                       (AS3 uint32_t*)(buf + c * 512), 16, 0, 0);
    }
  };

  auto compute = [&](const unsigned short* L) {
    short8 af[4], bf[4];
#pragma unroll
    for (int i = 0; i < 4; ++i)
      af[i] = *(const short8*)&L[(wr * 4 + i) * 512 + lane * 8];
#pragma unroll
    for (int j = 0; j < 4; ++j)
      bf[j] = *(const short8*)&L[(8 + wc * 4 + j) * 512 + lane * 8];
#pragma unroll
    for (int i = 0; i < 4; ++i)
#pragma unroll
      for (int j = 0; j < 4; ++j) acc[i][j] = mfma16(af[i], bf[j], acc[i][j]);
  };

  stage(lds[0], 0);
  stage(lds[1], 1);

  const int T = K >> 5;  // 32
  int bt = 0;            // t % 3
  for (int t = 0; t < T - 1; ++t) {
    asm volatile("s_waitcnt vmcnt(4)" ::: "memory");
    __builtin_amdgcn_sched_barrier(0);
    __builtin_amdgcn_s_barrier();
    __builtin_amdgcn_sched_barrier(0);
    if (t + 2 < T) {
      int b2 = (bt + 2 >= 3) ? bt - 1 : bt + 2;
      stage(lds[b2], t + 2);
    }
    compute(lds[bt]);
    bt = (bt + 1 == 3) ? 0 : bt + 1;
  }
  asm volatile("s_waitcnt vmcnt(0)" ::: "memory");
  __builtin_amdgcn_sched_barrier(0);
  __builtin_amdgcn_s_barrier();
  __builtin_amdgcn_sched_barrier(0);
  compute(lds[bt]);

  // Epilogue: scatter into attn-native Qb/Kb/Vh. which is tile-uniform
  // (1024-boundaries are 128-aligned). Same scalar-store cost as before.
  const int which = tn >> 10;  // 0=Q, 1=K, 2=V
  const int r0 = (lane >> 4) * 4;
#pragma unroll
  for (int i = 0; i < 4; ++i)
#pragma unroll
    for (int j = 0; j < 4; ++j)
#pragma unroll
      for (int r = 0; r < 4; ++r) {
        int row = tm + wr * 64 + i * 16 + r0 + r;
        int col = tn + wc * 64 + j * 16 + lrow;
        int h = (col >> 6) & 15, dd = col & 63;
        unsigned short v = f2bf(acc[i][j][r]);
        if (which == 0)
          Qb[qk_off(h, row, dd)] = v;
        else if (which == 1)
          Kb[qk_off(h, row, dd)] = v;
        else
          Vh[((size_t)h * 4096 + row) * 64 + dd] = v;
      }
}

// ---------------------------------------------------------------------------
// GEMM 64x128 tile (output projection). Unchanged from round 5.
// ---------------------------------------------------------------------------
__global__ __launch_bounds__(256) void gemm64(const unsigned short* __restrict__ A,
                                              const unsigned short* __restrict__ Bm,
                                              float* __restrict__ C, int N, int K) {
  __shared__ unsigned short lds[3][12 * 512];  // A: chunks 0-3, B: 4-11
  const int tid = threadIdx.x;
  const int lane = tid & 63;
  const int w = tid >> 6;
  const int wr = w >> 1, wc = w & 1;

  const int lid = blockIdx.y * gridDim.x + blockIdx.x;
  const int xcd = lid & 7;
  const int wgid = xcd * 64 + (lid >> 3);  // 0..511, contiguous per XCD
  const int s = wgid >> 5, w5 = wgid & 31; // supertile 0..15, within 0..31
  const int mt = (s & 3) * 16 + (w5 & 15); // 0..63
  const int nt = (s >> 2) * 2 + (w5 >> 4); // 0..7
  const int tm = mt * 64, tn = nt * 128;
  const int lrow = lane & 15;

  floatx4 acc[2][4];
#pragma unroll
  for (int i = 0; i < 2; ++i)
#pragma unroll
    for (int j = 0; j < 4; ++j) acc[i][j] = floatx4{0.f, 0.f, 0.f, 0.f};

  auto stage = [&](unsigned short* buf, int t) {
#pragma unroll
    for (int c = w * 3; c < w * 3 + 3; ++c) {
      const unsigned short* g;
      if (c < 4)
        g = A + ((size_t)(((mt >> 1) * 32 + t) * 8 + ((mt & 1) * 4 + c)) << 9) + lane * 8;
      else
        g = Bm + ((size_t)((nt * 32 + t) * 8 + (c - 4)) << 9) + lane * 8;
      __builtin_amdgcn_global_load_lds((const AS1 uint32_t*)g,
                                       (AS3 uint32_t*)(buf + c * 512), 16, 0, 0);
    }
  };

  auto compute = [&](const unsigned short* L) {
    short8 af[2], bf[4];
#pragma unroll
    for (int i = 0; i < 2; ++i)
      af[i] = *(const short8*)&L[(wr * 2 + i) * 512 + lane * 8];
#pragma unroll
    for (int j = 0; j < 4; ++j)
      bf[j] = *(const short8*)&L[(4 + wc * 4 + j) * 512 + lane * 8];
#pragma unroll
    for (int i = 0; i < 2; ++i)
#pragma unroll
      for (int j = 0; j < 4; ++j) acc[i][j] = mfma16(af[i], bf[j], acc[i][j]);
  };

  stage(lds[0], 0);
  stage(lds[1], 1);

  const int T = K >> 5;  // 32
  int bt = 0;
  for (int t = 0; t < T - 1; ++t) {
    asm volatile("s_waitcnt vmcnt(3)" ::: "memory");
    __builtin_amdgcn_sched_barrier(0);
    __builtin_amdgcn_s_barrier();
    __builtin_amdgcn_sched_barrier(0);
    if (t + 2 < T) {
      int b2 = (bt + 2 >= 3) ? bt - 1 : bt + 2;
      stage(lds[b2], t + 2);
    }
    compute(lds[bt]);
    bt = (bt + 1 == 3) ? 0 : bt + 1;
  }
  asm volatile("s_waitcnt vmcnt(0)" ::: "memory");
  __builtin_amdgcn_sched_barrier(0);
  __builtin_amdgcn_s_barrier();
  __builtin_amdgcn_sched_barrier(0);
  compute(lds[bt]);

  const int r0 = (lane >> 4) * 4;
#pragma unroll
  for (int i = 0; i < 2; ++i)
#pragma unroll
    for (int j = 0; j < 4; ++j)
#pragma unroll
      for (int r = 0; r < 4; ++r) {
        int row = tm + (wr * 2 + i) * 16 + r0 + r;
        int col = tn + (wc * 4 + j) * 16 + lrow;
        C[(size_t)row * N + col] = acc[i][j][r];
      }
}

// ---------------------------------------------------------------------------
// Flash attention, S^T orientation, 128 q/WG, 128-key blocks + 16-key sink.
// Inputs now attn-native: Qb/Kb chunk-tiled (all K staging + Q fragment
// loads are contiguous 1-KB lane-linear), Vh per-head row-major (dense
// 128-B rows). Window blocks aligned to q0-512 (16/128-aligned, same block
// count as q0-511; visibility masking unchanged/correct).
// ---------------------------------------------------------------------------
__global__ __launch_bounds__(256) void attn_kernel(const unsigned short* __restrict__ Qb,
                                                   const unsigned short* __restrict__ Kb,
                                                   const unsigned short* __restrict__ Vh,
                                                   unsigned short* __restrict__ aout) {
  __shared__ unsigned short Klds[2][16 * 512];  // 2 x 16KB A-frag chunks
  __shared__ unsigned short VT[64 * 136];       // V^T [d][key], stride 136
  __shared__ unsigned short PT[4][16 * 136];    // per-wave P^T [q][key]

  const int tid = threadIdx.x;
  const int lane = tid & 63;
  const int w = tid >> 6;
  const int lrow = lane & 15;
  const int lkg = lane >> 4;

  const int i = blockIdx.x;
  const int half = i >> 8;
  const int j = (i >> 3) & 31;
  const int h = 2 * (i & 7) + half;
  const int qb = half ? (31 - j) : j;
  const int q0 = qb * 128;

  // Q fragments: chunk-tiled -> contiguous lane-linear reads.
  short8 qf[2][2];
#pragma unroll
  for (int qt = 0; qt < 2; ++qt)
#pragma unroll
    for (int ks = 0; ks < 2; ++ks)
      qf[qt][ks] = *(const short8*)&Qb[((size_t)((h * 256 + (q0 >> 4) + qt * 4 + w) * 2 + ks)
                                        << 9) + lane * 8];

  float m_i[2], l_i[2];
  floatx4 o[4][2];
#pragma unroll
  for (int qt = 0; qt < 2; ++qt) {
    m_i[qt] = -1e30f;
    l_i[qt] = 0.f;
#pragma unroll
    for (int nt = 0; nt < 4; ++nt) o[nt][qt] = floatx4{0.f, 0.f, 0.f, 0.f};
  }

  const float scale2 = 0.125f * 1.44269504088896f;  // 1/sqrt(64) * log2(e)

  // ---- prologue: stage sink K/V; prefetch window block 0 ----
  if (w < 2) {  // sink K chunks (kg=0, ks=w) into Klds[0]
    const unsigned short* g = Kb + ((size_t)((h * 256 + 0) * 2 + w) << 9) + lane * 8;
    __builtin_amdgcn_global_load_lds((const AS1 uint32_t*)g,
                                     (AS3 uint32_t*)(&Klds[0][w * 512]), 16, 0, 0);
  }
  {  // sink V^T keys 0..31 (PV spans 0..31; P=0 for 16..31)
    if (lane < 16) {
      const unsigned short* g0 = Vh + ((size_t)h * 4096 + 2 * lane) * 64 + w * 16;
      ushort8 a0 = *(const ushort8*)g0;
      ushort8 a1 = *(const ushort8*)(g0 + 8);
      ushort8 b0 = *(const ushort8*)(g0 + 64);
      ushort8 b1 = *(const ushort8*)(g0 + 72);
      uint32_t* vt = (uint32_t*)VT;
#pragma unroll
      for (int dd = 0; dd < 8; ++dd) {
        vt[(w * 16 + dd) * 68 + lane] = (uint32_t)a0[dd] | ((uint32_t)b0[dd] << 16);
        vt[(w * 16 + 8 + dd) * 68 + lane] = (uint32_t)a1[dd] | ((uint32_t)b1[dd] << 16);
      }
    }
  }
  // window start: 16/128-aligned (q0-512 instead of q0-511; same block count)
  const int kb0 = (q0 - 512 < 16) ? 16 : (q0 - 512);
  // prefetch window block 0: K -> Klds[1], V -> registers
#pragma unroll
  for (int c = 0; c < 4; ++c) {
    int ch = w * 4 + c;
    int kt = ch >> 1, ks = ch & 1;
    const unsigned short* g =
        Kb + ((size_t)((h * 256 + (kb0 >> 4) + kt) * 2 + ks) << 9) + lane * 8;
    __builtin_amdgcn_global_load_lds((const AS1 uint32_t*)g,
                                     (AS3 uint32_t*)(&Klds[1][ch * 512]), 16, 0, 0);
  }
  ushort8 va0, va1, vb0, vb1;
  {
    const unsigned short* g0 = Vh + ((size_t)h * 4096 + kb0 + 2 * lane) * 64 + w * 16;
    va0 = *(const ushort8*)g0;
    va1 = *(const ushort8*)(g0 + 8);
    vb0 = *(const ushort8*)(g0 + 64);
    vb1 = *(const ushort8*)(g0 + 72);
  }
  __syncthreads();

  // ---- sink compute (keys 0..15; PV over 0..31 with P=0 padding) ----
#pragma unroll
  for (int qt = 0; qt < 2; ++qt) {
    const int qq = q0 + qt * 64 + w * 16 + lrow;
    floatx4 s0 = floatx4{0.f, 0.f, 0.f, 0.f};
#pragma unroll
    for (int ks = 0; ks < 2; ++ks) {
      short8 kf = *(const short8*)&Klds[0][ks * 512 + lane * 8];
      s0 = mfma16(kf, qf[qt][ks], s0);
    }
    float mx = -1e30f;
    float sv[4];
#pragma unroll
    for (int r = 0; r < 4; ++r) {
      int key = lkg * 4 + r;
      bool vis = (key <= qq) && ((key < 4) || (key >= qq - 511));
      sv[r] = vis ? s0[r] * scale2 : -1e30f;
      mx = fmaxf(mx, sv[r]);
    }
    mx = fmaxf(mx, __shfl_xor(mx, 16));
    mx = fmaxf(mx, __shfl_xor(mx, 32));
    m_i[qt] = mx;  // key 0 always visible -> finite
    float p0 = exp2f(sv[0] - mx), p1 = exp2f(sv[1] - mx);
    float p2 = exp2f(sv[2] - mx), p3 = exp2f(sv[3] - mx);
    float ps = (p0 + p1) + (p2 + p3);
    *(uint2*)&PT[w][lrow * 136 + lkg * 4] = uint2{cvt_pk_bf16(p0, p1), cvt_pk_bf16(p2, p3)};
    *(uint2*)&PT[w][lrow * 136 + 16 + lkg * 4] = uint2{0u, 0u};  // keys 16..31 = 0
    ps += __shfl_xor(ps, 16);
    ps += __shfl_xor(ps, 32);
    l_i[qt] = ps;
    short8 pf = *(const short8*)&PT[w][lrow * 136 + lkg * 8];
#pragma unroll
    for (int nt = 0; nt < 4; ++nt) {
      short8 vf = *(const short8*)&VT[(nt * 16 + lrow) * 136 + lkg * 8];
      o[nt][qt] = mfma16(vf, pf, o[nt][qt]);
    }
  }

  // ---- window blocks of 128 keys (pipelined) ----
  int nbuf = 1;
  for (int kb = kb0; kb < q0 + 128; kb += 128) {
    const bool hasnext = (kb + 128 < q0 + 128);
    __syncthreads();  // prev readers of VT done; this block's K/V prefetch drained (landed)
    {  // write V^T for this block from prefetched registers
      uint32_t* vt = (uint32_t*)VT;
#pragma unroll
      for (int dd = 0; dd < 8; ++dd) {
        vt[(w * 16 + dd) * 68 + lane] = (uint32_t)va0[dd] | ((uint32_t)vb0[dd] << 16);
        vt[(w * 16 + 8 + dd) * 68 + lane] = (uint32_t)va1[dd] | ((uint32_t)vb1[dd] << 16);
      }
    }
    __syncthreads();  // VT visible

    // issue prefetches for block n+1 (land during this block's compute)
    if (hasnext) {
      const int kn = kb + 128;
#pragma unroll
      for (int c = 0; c < 4; ++c) {
        int ch = w * 4 + c;
        int kt = ch >> 1, ks = ch & 1;
        const unsigned short* g =
            Kb + ((size_t)((h * 256 + (kn >> 4) + kt) * 2 + ks) << 9) + lane * 8;
        __builtin_amdgcn_global_load_lds((const AS1 uint32_t*)g,
                                         (AS3 uint32_t*)(&Klds[1 - nbuf][ch * 512]), 16, 0, 0);
      }
      const unsigned short* g0 = Vh + ((size_t)h * 4096 + kn + 2 * lane) * 64 + w * 16;
      va0 = *(const ushort8*)g0;
      va1 = *(const ushort8*)(g0 + 8);
      vb0 = *(const ushort8*)(g0 + 64);
      vb1 = *(const ushort8*)(g0 + 72);
    }

#pragma unroll
    for (int qt = 0; qt < 2; ++qt) {
      const int qaT = q0 + qt * 64 + w * 16;  // wave-uniform
      const int qq = qaT + lrow;
      floatx4 s[8];
#pragma unroll
      for (int ct = 0; ct < 8; ++ct) {
        s[ct] = floatx4{0.f, 0.f, 0.f, 0.f};
#pragma unroll
        for (int ks = 0; ks < 2; ++ks) {
          short8 kf = *(const short8*)&Klds[nbuf][(ct * 2 + ks) * 512 + lane * 8];
          s[ct] = mfma16(kf, qf[qt][ks], s[ct]);
        }
      }
      const bool full = (kb + 127 <= qaT) && (kb >= qaT + 15 - 511);
      float mx = -1e30f;
#pragma unroll
      for (int ct = 0; ct < 8; ++ct)
#pragma unroll
        for (int r = 0; r < 4; ++r) {
          float val = s[ct][r] * scale2;
          if (!full) {
            int key = kb + ct * 16 + lkg * 4 + r;
            bool vis = (key <= qq) && (key >= qq - 511);
            val = vis ? val : -1e30f;
          }
          s[ct][r] = val;
          mx = fmaxf(mx, val);
        }
      mx = fmaxf(mx, __shfl_xor(mx, 16));
      mx = fmaxf(mx, __shfl_xor(mx, 32));
      float nm = fmaxf(m_i[qt], mx);
      float alpha = exp2f(m_i[qt] - nm);
      m_i[qt] = nm;

      float ps = 0.f;
#pragma unroll
      for (int ct = 0; ct < 8; ++ct) {
        float p0 = exp2f(s[ct][0] - nm), p1 = exp2f(s[ct][1] - nm);
        float p2 = exp2f(s[ct][2] - nm), p3 = exp2f(s[ct][3] - nm);
        ps += (p0 + p1) + (p2 + p3);
        *(uint2*)&PT[w][lrow * 136 + ct * 16 + lkg * 4] =
            uint2{cvt_pk_bf16(p0, p1), cvt_pk_bf16(p2, p3)};
      }
      ps += __shfl_xor(ps, 16);
      ps += __shfl_xor(ps, 32);
      l_i[qt] = l_i[qt] * alpha + ps;

#pragma unroll
      for (int nt = 0; nt < 4; ++nt)
#pragma unroll
        for (int r = 0; r < 4; ++r) o[nt][qt][r] *= alpha;

#pragma unroll
      for (int kk = 0; kk < 4; ++kk) {
        short8 pf = *(const short8*)&PT[w][lrow * 136 + kk * 32 + lkg * 8];
#pragma unroll
        for (int nt = 0; nt < 4; ++nt) {
          short8 vf = *(const short8*)&VT[(nt * 16 + lrow) * 136 + kk * 32 + lkg * 8];
          o[nt][qt] = mfma16(vf, pf, o[nt][qt]);
        }
      }
    }
    nbuf ^= 1;
  }

  // ---- epilogue: write AO in staging-tiled layout for gemm64 ----
#pragma unroll
  for (int qt = 0; qt < 2; ++qt) {
    const int qq = q0 + qt * 64 + w * 16 + lrow;
    const float inv = 1.0f / l_i[qt];
#pragma unroll
    for (int nt = 0; nt < 4; ++nt) {
      floatx4 ov = o[nt][qt];
      uint32_t lo = cvt_pk_bf16(ov[0] * inv, ov[1] * inv);
      uint32_t hi = cvt_pk_bf16(ov[2] * inv, ov[3] * inv);
      int col = h * 64 + nt * 16 + lkg * 4;
      *(uint2*)&aout[tiled_off(qq, col)] = uint2{lo, hi};
    }
  }
}

// ---------------------------------------------------------------------------
extern "C" void kernel_launch(void* const* d_in, const int* in_sizes, int n_in,
                              void* d_out, int out_size, void* d_ws, size_t ws_size,
                              hipStream_t stream) {
  const float* x = (const float*)d_in[0];
  const float* wq = (const float*)d_in[1];
  const float* wk = (const float*)d_in[2];
  const float* wv = (const float*)d_in[3];
  const float* wo = (const float*)d_in[4];

  char* ws = (char*)d_ws;
  unsigned short* Xb = (unsigned short*)(ws);                 // 8 MB (tiled)
  unsigned short* Wqkv = (unsigned short*)(ws + (8u << 20));  // 6 MB (tiled)
  unsigned short* Wob = (unsigned short*)(ws + (14u << 20));  // 2 MB (tiled)
  unsigned short* Qb = (unsigned short*)(ws + (16u << 20));   // 8 MB (chunk-tiled)
  unsigned short* Kb = (unsigned short*)(ws + (24u << 20));   // 8 MB (chunk-tiled)
  unsigned short* Vh = (unsigned short*)(ws + (32u << 20));   // 8 MB (per-head rows)
  unsigned short* AO = (unsigned short*)(ws + (40u << 20));   // 8 MB (tiled)

  convert_pack<<<4096, 256, 0, stream>>>(x, wq, wk, wv, wo, Xb, Wqkv, Wob);
  gemm_qkv<<<dim3(32, 24), 256, 0, stream>>>(Xb, Wqkv, Qb, Kb, Vh, 1024);
  attn_kernel<<<512, 256, 0, stream>>>(Qb, Kb, Vh, AO);
  gemm64<<<dim3(64, 8), 256, 0, stream>>>(AO, Wob, (float*)d_out, 1024, 1024);
}

// Round 8
// 161.653 us; speedup vs baseline: 1.0377x; 1.0262x over previous
//
#include <hip/hip_runtime.h>
#include <stdint.h>

#define AS1 __attribute__((address_space(1)))
#define AS3 __attribute__((address_space(3)))

typedef short short8 __attribute__((ext_vector_type(8)));
typedef unsigned short ushort8 __attribute__((ext_vector_type(8)));
typedef __bf16 bf16x8 __attribute__((ext_vector_type(8)));
typedef float floatx4 __attribute__((ext_vector_type(4)));

__device__ __forceinline__ floatx4 mfma16(short8 a, short8 b, floatx4 c) {
  return __builtin_amdgcn_mfma_f32_16x16x32_bf16(
      __builtin_bit_cast(bf16x8, a), __builtin_bit_cast(bf16x8, b), c, 0, 0, 0);
}

__device__ __forceinline__ unsigned short f2bf(float f) {
  uint32_t u = __builtin_bit_cast(uint32_t, f);
  u = (u + 0x7FFFu + ((u >> 16) & 1u)) >> 16;
  return (unsigned short)u;
}

// packed f32x2 -> bf16x2, 1 VALU instr for 2 values
__device__ __forceinline__ uint32_t cvt_pk_bf16(float a, float b) {
  uint32_t d;
  asm("v_cvt_pk_bf16_f32 %0, %1, %2" : "=v"(d) : "v"(a), "v"(b));
  return d;
}

// ---------------------------------------------------------------------------
// Staging-tiled layout (HW-validated R4/R5): 1-KB lane-linear blocks.
// ---------------------------------------------------------------------------
__device__ __forceinline__ size_t tiled_off(int row, int col) {
  int rt = row >> 7, c8 = (row >> 4) & 7, rr = row & 15;
  int t = col >> 5, lh = (col >> 3) & 3, e = col & 7;
  return ((size_t)((rt * 32 + t) * 8 + c8) << 9) + (lh * 16 + rr) * 8 + e;
}

// ---------------------------------------------------------------------------
// Convert/pack v3: one WAVE per 1-KB output block (R5-proven).
// ---------------------------------------------------------------------------
__global__ __launch_bounds__(256) void convert_pack(
    const float* __restrict__ x, const float* __restrict__ wq,
    const float* __restrict__ wk, const float* __restrict__ wv,
    const float* __restrict__ wo, unsigned short* __restrict__ xb,
    unsigned short* __restrict__ wqkvb, unsigned short* __restrict__ wob) {
  const int lane = threadIdx.x & 63;
  const int wid = threadIdx.x >> 6;
  const int b = blockIdx.x * 4 + wid;  // 0..16383
  const int lrow = lane & 15, lkg = lane >> 4;
  const float* src;
  unsigned short* dst;
  if (b < 8192) {  // x: 4096x1024
    int rt = b >> 8, wi = b & 255, t = wi >> 3, c8 = wi & 7;
    int row = rt * 128 + c8 * 16 + lrow;
    src = x + (size_t)row * 1024 + t * 32 + lkg * 8;
    dst = xb + ((size_t)b << 9) + lane * 8;
  } else if (b < 14336) {  // Wq|Wk|Wv -> Wqkv rows 0..3071
    int jb = b - 8192;
    int rt = jb >> 8, wi = jb & 255, t = wi >> 3, c8 = wi & 7;
    int row = rt * 128 + c8 * 16 + lrow;  // 0..3071
    int r = row >> 10, srow = row & 1023;
    const float* m = (r == 0) ? wq : (r == 1) ? wk : wv;
    src = m + (size_t)srow * 1024 + t * 32 + lkg * 8;
    dst = wqkvb + ((size_t)jb << 9) + lane * 8;
  } else {  // Wo: 1024x1024
    int jb = b - 14336;
    int rt = jb >> 8, wi = jb & 255, t = wi >> 3, c8 = wi & 7;
    int row = rt * 128 + c8 * 16 + lrow;
    src = wo + (size_t)row * 1024 + t * 32 + lkg * 8;
    dst = wob + ((size_t)jb << 9) + lane * 8;
  }
  float4 a = *(const float4*)src;
  float4 c = *(const float4*)(src + 4);
  ushort8 o;
  o[0] = f2bf(a.x); o[1] = f2bf(a.y); o[2] = f2bf(a.z); o[3] = f2bf(a.w);
  o[4] = f2bf(c.x); o[5] = f2bf(c.y); o[6] = f2bf(c.z); o[7] = f2bf(c.w);
  *(ushort8*)dst = o;
}

// ---------------------------------------------------------------------------
// GEMM 128x128 tile (QKV projection): C[M][N] = A[M][K] @ B[N][K]^T.
// Exact R5 structure (best measured: 159.2us total). A/B staging-tiled;
// 3 x 16KB buffers, depth-2 counted-vmcnt pipeline, XCD-compact swizzle.
// Row-major C epilogue (R7's attn-native scatter epilogue cost +6.7us; the
// attn-native layouts were null because attn is L2-resident + VALU-bound).
// ---------------------------------------------------------------------------
template <typename OutT>
__global__ __launch_bounds__(256) void gemm_bt(const unsigned short* __restrict__ A,
                                               const unsigned short* __restrict__ Bm,
                                               OutT* __restrict__ C, int N, int K) {
  __shared__ unsigned short lds[3][16 * 512];  // 3 x 16 KB (BK=32)
  const int tid = threadIdx.x;
  const int lane = tid & 63;
  const int w = tid >> 6;
  const int wr = w >> 1, wc = w & 1;

  // XCD-compact supertile swizzle for grid (32,24)=768 (bijective).
  const int lid = blockIdx.y * gridDim.x + blockIdx.x;
  const int xcd = lid & 7;
  const int wgid = xcd * 96 + (lid >> 3);  // 0..767, contiguous per XCD
  const int s = wgid >> 5, w5 = wgid & 31; // supertile 0..23, within 0..31
  const int mt = (s & 3) * 8 + (w5 & 7);   // 0..31
  const int nt = (s >> 2) * 4 + (w5 >> 3); // 0..23
  const int tm = mt * 128, tn = nt * 128;
  const int lrow = lane & 15;

  floatx4 acc[4][4];
#pragma unroll
  for (int i = 0; i < 4; ++i)
#pragma unroll
    for (int j = 0; j < 4; ++j) acc[i][j] = floatx4{0.f, 0.f, 0.f, 0.f};

  auto stage = [&](unsigned short* buf, int t) {
#pragma unroll
    for (int c = w * 4; c < w * 4 + 4; ++c) {
      const unsigned short* g;
      if (c < 8)
        g = A + ((size_t)((mt * 32 + t) * 8 + c) << 9) + lane * 8;
      else
        g = Bm + ((size_t)((nt * 32 + t) * 8 + (c - 8)) << 9) + lane * 8;
      __builtin_amdgcn_global_load_lds((const AS1 uint32_t*)g,
                                       (AS3 uint32_t*)(buf + c * 512), 16, 0, 0);
    }
  };

  auto compute = [&](const unsigned short* L) {
    short8 af[4], bf[4];
#pragma unroll
    for (int i = 0; i < 4; ++i)
      af[i] = *(const short8*)&L[(wr * 4 + i) * 512 + lane * 8];
#pragma unroll
    for (int j = 0; j < 4; ++j)
      bf[j] = *(const short8*)&L[(8 + wc * 4 + j) * 512 + lane * 8];
#pragma unroll
    for (int i = 0; i < 4; ++i)
#pragma unroll
      for (int j = 0; j < 4; ++j) acc[i][j] = mfma16(af[i], bf[j], acc[i][j]);
  };

  stage(lds[0], 0);
  stage(lds[1], 1);

  const int T = K >> 5;  // 32
  int bt = 0;            // t % 3
  for (int t = 0; t < T - 1; ++t) {
    asm volatile("s_waitcnt vmcnt(4)" ::: "memory");
    __builtin_amdgcn_sched_barrier(0);
    __builtin_amdgcn_s_barrier();
    __builtin_amdgcn_sched_barrier(0);
    if (t + 2 < T) {
      int b2 = (bt + 2 >= 3) ? bt - 1 : bt + 2;
      stage(lds[b2], t + 2);
    }
    compute(lds[bt]);
    bt = (bt + 1 == 3) ? 0 : bt + 1;
  }
  asm volatile("s_waitcnt vmcnt(0)" ::: "memory");
  __builtin_amdgcn_sched_barrier(0);
  __builtin_amdgcn_s_barrier();
  __builtin_amdgcn_sched_barrier(0);
  compute(lds[bt]);

  const int r0 = (lane >> 4) * 4;
#pragma unroll
  for (int i = 0; i < 4; ++i)
#pragma unroll
    for (int j = 0; j < 4; ++j)
#pragma unroll
      for (int r = 0; r < 4; ++r) {
        int row = tm + wr * 64 + i * 16 + r0 + r;
        int col = tn + wc * 64 + j * 16 + lrow;
        float v = acc[i][j][r];
        if constexpr (sizeof(OutT) == 2)
          C[(size_t)row * N + col] = f2bf(v);
        else
          C[(size_t)row * N + col] = v;
      }
}

// ---------------------------------------------------------------------------
// GEMM 64x128 tile (output projection). Exact R5 version (both sides
// staging-tiled; counted-vmcnt 3-buffer pipeline).
// ---------------------------------------------------------------------------
__global__ __launch_bounds__(256) void gemm64(const unsigned short* __restrict__ A,
                                              const unsigned short* __restrict__ Bm,
                                              float* __restrict__ C, int N, int K) {
  __shared__ unsigned short lds[3][12 * 512];  // A: chunks 0-3, B: 4-11
  const int tid = threadIdx.x;
  const int lane = tid & 63;
  const int w = tid >> 6;
  const int wr = w >> 1, wc = w & 1;

  const int lid = blockIdx.y * gridDim.x + blockIdx.x;
  const int xcd = lid & 7;
  const int wgid = xcd * 64 + (lid >> 3);  // 0..511, contiguous per XCD
  const int s = wgid >> 5, w5 = wgid & 31; // supertile 0..15, within 0..31
  const int mt = (s & 3) * 16 + (w5 & 15); // 0..63
  const int nt = (s >> 2) * 2 + (w5 >> 4); // 0..7
  const int tm = mt * 64, tn = nt * 128;
  const int lrow = lane & 15;

  floatx4 acc[2][4];
#pragma unroll
  for (int i = 0; i < 2; ++i)
#pragma unroll
    for (int j = 0; j < 4; ++j) acc[i][j] = floatx4{0.f, 0.f, 0.f, 0.f};

  auto stage = [&](unsigned short* buf, int t) {
#pragma unroll
    for (int c = w * 3; c < w * 3 + 3; ++c) {
      const unsigned short* g;
      if (c < 4)
        g = A + ((size_t)(((mt >> 1) * 32 + t) * 8 + ((mt & 1) * 4 + c)) << 9) + lane * 8;
      else
        g = Bm + ((size_t)((nt * 32 + t) * 8 + (c - 4)) << 9) + lane * 8;
      __builtin_amdgcn_global_load_lds((const AS1 uint32_t*)g,
                                       (AS3 uint32_t*)(buf + c * 512), 16, 0, 0);
    }
  };

  auto compute = [&](const unsigned short* L) {
    short8 af[2], bf[4];
#pragma unroll
    for (int i = 0; i < 2; ++i)
      af[i] = *(const short8*)&L[(wr * 2 + i) * 512 + lane * 8];
#pragma unroll
    for (int j = 0; j < 4; ++j)
      bf[j] = *(const short8*)&L[(4 + wc * 4 + j) * 512 + lane * 8];
#pragma unroll
    for (int i = 0; i < 2; ++i)
#pragma unroll
      for (int j = 0; j < 4; ++j) acc[i][j] = mfma16(af[i], bf[j], acc[i][j]);
  };

  stage(lds[0], 0);
  stage(lds[1], 1);

  const int T = K >> 5;  // 32
  int bt = 0;
  for (int t = 0; t < T - 1; ++t) {
    asm volatile("s_waitcnt vmcnt(3)" ::: "memory");
    __builtin_amdgcn_sched_barrier(0);
    __builtin_amdgcn_s_barrier();
    __builtin_amdgcn_sched_barrier(0);
    if (t + 2 < T) {
      int b2 = (bt + 2 >= 3) ? bt - 1 : bt + 2;
      stage(lds[b2], t + 2);
    }
    compute(lds[bt]);
    bt = (bt + 1 == 3) ? 0 : bt + 1;
  }
  asm volatile("s_waitcnt vmcnt(0)" ::: "memory");
  __builtin_amdgcn_sched_barrier(0);
  __builtin_amdgcn_s_barrier();
  __builtin_amdgcn_sched_barrier(0);
  compute(lds[bt]);

  const int r0 = (lane >> 4) * 4;
#pragma unroll
  for (int i = 0; i < 2; ++i)
#pragma unroll
    for (int j = 0; j < 4; ++j)
#pragma unroll
      for (int r = 0; r < 4; ++r) {
        int row = tm + (wr * 2 + i) * 16 + r0 + r;
        int col = tn + (wc * 4 + j) * 16 + lrow;
        C[(size_t)row * N + col] = acc[i][j][r];
      }
}

// ---------------------------------------------------------------------------
// Flash attention, S^T orientation, 128 q/WG, 128-key blocks + 16-key sink.
// R5 structure + two minimal VALU cuts (attn is softmax/VALU-bound):
//  - defer-max THR=0 (EXACT): if __all(mx <= m_i), alpha==1 -> skip max
//    update + O-rescale pass (multiply-by-1 elided; bit-identical).
//  - s_setprio(1) around QK^T and PV MFMA clusters (2 staggered WGs/CU).
// ---------------------------------------------------------------------------
__global__ __launch_bounds__(256) void attn_kernel(const unsigned short* __restrict__ qkv,
                                                   unsigned short* __restrict__ aout) {
  __shared__ unsigned short Klds[2][16 * 512];  // 2 x 16KB A-frag chunks
  __shared__ unsigned short VT[64 * 136];       // V^T [d][key], stride 136
  __shared__ unsigned short PT[4][16 * 136];    // per-wave P^T [q][key]

  const int tid = threadIdx.x;
  const int lane = tid & 63;
  const int w = tid >> 6;
  const int lrow = lane & 15;
  const int lkg = lane >> 4;

  const int i = blockIdx.x;
  const int half = i >> 8;
  const int j = (i >> 3) & 31;
  const int h = 2 * (i & 7) + half;
  const int qb = half ? (31 - j) : j;
  const int q0 = qb * 128;

  short8 qf[2][2];
#pragma unroll
  for (int qt = 0; qt < 2; ++qt)
#pragma unroll
    for (int ks = 0; ks < 2; ++ks)
      qf[qt][ks] = *(const short8*)&qkv[(size_t)(q0 + qt * 64 + w * 16 + lrow) * 3072 +
                                        h * 64 + ks * 32 + lkg * 8];

  float m_i[2], l_i[2];
  floatx4 o[4][2];
#pragma unroll
  for (int qt = 0; qt < 2; ++qt) {
    m_i[qt] = -1e30f;
    l_i[qt] = 0.f;
#pragma unroll
    for (int nt = 0; nt < 4; ++nt) o[nt][qt] = floatx4{0.f, 0.f, 0.f, 0.f};
  }

  const float scale2 = 0.125f * 1.44269504088896f;  // 1/sqrt(64) * log2(e)

  // ---- prologue: stage sink K/V; prefetch window block 0 ----
  if (w < 2) {  // sink K chunks 0,1 into Klds[0]
    const unsigned short* g = &qkv[(size_t)lrow * 3072 + 1024 + h * 64 + w * 32 + lkg * 8];
    __builtin_amdgcn_global_load_lds((const AS1 uint32_t*)g,
                                     (AS3 uint32_t*)(&Klds[0][w * 512]), 16, 0, 0);
  }
  {  // sink V^T keys 0..31 (PV spans 0..31; P=0 for 16..31)
    if (lane < 16) {
      const unsigned short* g0 = &qkv[(size_t)(2 * lane) * 3072 + 2048 + h * 64 + w * 16];
      ushort8 a0 = *(const ushort8*)g0;
      ushort8 a1 = *(const ushort8*)(g0 + 8);
      ushort8 b0 = *(const ushort8*)(g0 + 3072);
      ushort8 b1 = *(const ushort8*)(g0 + 3080);
      uint32_t* vt = (uint32_t*)VT;
#pragma unroll
      for (int dd = 0; dd < 8; ++dd) {
        vt[(w * 16 + dd) * 68 + lane] = (uint32_t)a0[dd] | ((uint32_t)b0[dd] << 16);
        vt[(w * 16 + 8 + dd) * 68 + lane] = (uint32_t)a1[dd] | ((uint32_t)b1[dd] << 16);
      }
    }
  }
  const int kb0 = (q0 - 511 < 16) ? 16 : (q0 - 511);
  // prefetch window block 0: K -> Klds[1], V -> registers
#pragma unroll
  for (int c = 0; c < 4; ++c) {
    int ch = w * 4 + c;
    int kt = ch >> 1, ks = ch & 1;
    const unsigned short* g =
        &qkv[(size_t)(kb0 + kt * 16 + lrow) * 3072 + 1024 + h * 64 + ks * 32 + lkg * 8];
    __builtin_amdgcn_global_load_lds((const AS1 uint32_t*)g,
                                     (AS3 uint32_t*)(&Klds[1][ch * 512]), 16, 0, 0);
  }
  ushort8 va0, va1, vb0, vb1;
  {
    const unsigned short* g0 = &qkv[(size_t)(kb0 + 2 * lane) * 3072 + 2048 + h * 64 + w * 16];
    va0 = *(const ushort8*)g0;
    va1 = *(const ushort8*)(g0 + 8);
    vb0 = *(const ushort8*)(g0 + 3072);
    vb1 = *(const ushort8*)(g0 + 3080);
  }
  __syncthreads();

  // ---- sink compute (keys 0..15; PV over 0..31 with P=0 padding) ----
#pragma unroll
  for (int qt = 0; qt < 2; ++qt) {
    const int qq = q0 + qt * 64 + w * 16 + lrow;
    floatx4 s0 = floatx4{0.f, 0.f, 0.f, 0.f};
#pragma unroll
    for (int ks = 0; ks < 2; ++ks) {
      short8 kf = *(const short8*)&Klds[0][ks * 512 + lane * 8];
      s0 = mfma16(kf, qf[qt][ks], s0);
    }
    float mx = -1e30f;
    float sv[4];
#pragma unroll
    for (int r = 0; r < 4; ++r) {
      int key = lkg * 4 + r;
      bool vis = (key <= qq) && ((key < 4) || (key >= qq - 511));
      sv[r] = vis ? s0[r] * scale2 : -1e30f;
      mx = fmaxf(mx, sv[r]);
    }
    mx = fmaxf(mx, __shfl_xor(mx, 16));
    mx = fmaxf(mx, __shfl_xor(mx, 32));
    m_i[qt] = mx;  // key 0 always visible -> finite
    float p0 = exp2f(sv[0] - mx), p1 = exp2f(sv[1] - mx);
    float p2 = exp2f(sv[2] - mx), p3 = exp2f(sv[3] - mx);
    float ps = (p0 + p1) + (p2 + p3);
    *(uint2*)&PT[w][lrow * 136 + lkg * 4] = uint2{cvt_pk_bf16(p0, p1), cvt_pk_bf16(p2, p3)};
    *(uint2*)&PT[w][lrow * 136 + 16 + lkg * 4] = uint2{0u, 0u};  // keys 16..31 = 0
    ps += __shfl_xor(ps, 16);
    ps += __shfl_xor(ps, 32);
    l_i[qt] = ps;
    short8 pf = *(const short8*)&PT[w][lrow * 136 + lkg * 8];
#pragma unroll
    for (int nt = 0; nt < 4; ++nt) {
      short8 vf = *(const short8*)&VT[(nt * 16 + lrow) * 136 + lkg * 8];
      o[nt][qt] = mfma16(vf, pf, o[nt][qt]);
    }
  }

  // ---- window blocks of 128 keys (pipelined) ----
  int nbuf = 1;
  for (int kb = kb0; kb < q0 + 128; kb += 128) {
    const bool hasnext = (kb + 128 < q0 + 128);
    __syncthreads();  // prev readers of VT done; this block's K/V prefetch drained (landed)
    {  // write V^T for this block from prefetched registers
      uint32_t* vt = (uint32_t*)VT;
#pragma unroll
      for (int dd = 0; dd < 8; ++dd) {
        vt[(w * 16 + dd) * 68 + lane] = (uint32_t)va0[dd] | ((uint32_t)vb0[dd] << 16);
        vt[(w * 16 + 8 + dd) * 68 + lane] = (uint32_t)va1[dd] | ((uint32_t)vb1[dd] << 16);
      }
    }
    __syncthreads();  // VT visible

    // issue prefetches for block n+1 (land during this block's compute)
    if (hasnext) {
      const int kn = kb + 128;
#pragma unroll
      for (int c = 0; c < 4; ++c) {
        int ch = w * 4 + c;
        int kt = ch >> 1, ks = ch & 1;
        const unsigned short* g =
            &qkv[(size_t)(kn + kt * 16 + lrow) * 3072 + 1024 + h * 64 + ks * 32 + lkg * 8];
        __builtin_amdgcn_global_load_lds((const AS1 uint32_t*)g,
                                         (AS3 uint32_t*)(&Klds[1 - nbuf][ch * 512]), 16, 0, 0);
      }
      const unsigned short* g0 = &qkv[(size_t)(kn + 2 * lane) * 3072 + 2048 + h * 64 + w * 16];
      va0 = *(const ushort8*)g0;
      va1 = *(const ushort8*)(g0 + 8);
      vb0 = *(const ushort8*)(g0 + 3072);
      vb1 = *(const ushort8*)(g0 + 3080);
    }

#pragma unroll
    for (int qt = 0; qt < 2; ++qt) {
      const int qaT = q0 + qt * 64 + w * 16;  // wave-uniform
      const int qq = qaT + lrow;
      floatx4 s[8];
      __builtin_amdgcn_s_setprio(1);
#pragma unroll
      for (int ct = 0; ct < 8; ++ct) {
        s[ct] = floatx4{0.f, 0.f, 0.f, 0.f};
#pragma unroll
        for (int ks = 0; ks < 2; ++ks) {
          short8 kf = *(const short8*)&Klds[nbuf][(ct * 2 + ks) * 512 + lane * 8];
          s[ct] = mfma16(kf, qf[qt][ks], s[ct]);
        }
      }
      __builtin_amdgcn_s_setprio(0);
      const bool full = (kb + 127 <= qaT) && (kb >= qaT + 15 - 511);
      float mx = -1e30f;
#pragma unroll
      for (int ct = 0; ct < 8; ++ct)
#pragma unroll
        for (int r = 0; r < 4; ++r) {
          float val = s[ct][r] * scale2;
          if (!full) {
            int key = kb + ct * 16 + lkg * 4 + r;
            bool vis = (key <= qq) && (key >= qq - 511);
            val = vis ? val : -1e30f;
          }
          s[ct][r] = val;
          mx = fmaxf(mx, val);
        }
      mx = fmaxf(mx, __shfl_xor(mx, 16));
      mx = fmaxf(mx, __shfl_xor(mx, 32));

      // defer-max THR=0 (exact): if no lane's max grew, alpha==1 -> skip
      // the max update and the O-rescale pass entirely.
      float nm = m_i[qt];
      if (!__all(mx <= nm)) {
        nm = fmaxf(nm, mx);
        float alpha = exp2f(m_i[qt] - nm);
        m_i[qt] = nm;
        l_i[qt] *= alpha;
#pragma unroll
        for (int nt = 0; nt < 4; ++nt)
#pragma unroll
          for (int r = 0; r < 4; ++r) o[nt][qt][r] *= alpha;
      }

      float ps = 0.f;
#pragma unroll
      for (int ct = 0; ct < 8; ++ct) {
        float p0 = exp2f(s[ct][0] - nm), p1 = exp2f(s[ct][1] - nm);
        float p2 = exp2f(s[ct][2] - nm), p3 = exp2f(s[ct][3] - nm);
        ps += (p0 + p1) + (p2 + p3);
        *(uint2*)&PT[w][lrow * 136 + ct * 16 + lkg * 4] =
            uint2{cvt_pk_bf16(p0, p1), cvt_pk_bf16(p2, p3)};
      }
      ps += __shfl_xor(ps, 16);
      ps += __shfl_xor(ps, 32);
      l_i[qt] = l_i[qt] + ps;

      __builtin_amdgcn_s_setprio(1);
#pragma unroll
      for (int kk = 0; kk < 4; ++kk) {
        short8 pf = *(const short8*)&PT[w][lrow * 136 + kk * 32 + lkg * 8];
#pragma unroll
        for (int nt = 0; nt < 4; ++nt) {
          short8 vf = *(const short8*)&VT[(nt * 16 + lrow) * 136 + kk * 32 + lkg * 8];
          o[nt][qt] = mfma16(vf, pf, o[nt][qt]);
        }
      }
      __builtin_amdgcn_s_setprio(0);
    }
    nbuf ^= 1;
  }

  // ---- epilogue: write AO in staging-tiled layout for gemm64 ----
#pragma unroll
  for (int qt = 0; qt < 2; ++qt) {
    const int qq = q0 + qt * 64 + w * 16 + lrow;
    const float inv = 1.0f / l_i[qt];
#pragma unroll
    for (int nt = 0; nt < 4; ++nt) {
      floatx4 ov = o[nt][qt];
      uint32_t lo = cvt_pk_bf16(ov[0] * inv, ov[1] * inv);
      uint32_t hi = cvt_pk_bf16(ov[2] * inv, ov[3] * inv);
      int col = h * 64 + nt * 16 + lkg * 4;
      *(uint2*)&aout[tiled_off(qq, col)] = uint2{lo, hi};
    }
  }
}

// ---------------------------------------------------------------------------
extern "C" void kernel_launch(void* const* d_in, const int* in_sizes, int n_in,
                              void* d_out, int out_size, void* d_ws, size_t ws_size,
                              hipStream_t stream) {
  const float* x = (const float*)d_in[0];
  const float* wq = (const float*)d_in[1];
  const float* wk = (const float*)d_in[2];
  const float* wv = (const float*)d_in[3];
  const float* wo = (const float*)d_in[4];

  char* ws = (char*)d_ws;
  unsigned short* Xb = (unsigned short*)(ws);                 // 8 MB (tiled)
  unsigned short* Wqkv = (unsigned short*)(ws + (8u << 20));  // 6 MB (tiled)
  unsigned short* Wob = (unsigned short*)(ws + (14u << 20));  // 2 MB (tiled)
  unsigned short* QKV = (unsigned short*)(ws + (16u << 20));  // 24 MB
  unsigned short* AO = (unsigned short*)(ws + (40u << 20));   // 8 MB (tiled)

  convert_pack<<<4096, 256, 0, stream>>>(x, wq, wk, wv, wo, Xb, Wqkv, Wob);
  gemm_bt<unsigned short><<<dim3(32, 24), 256, 0, stream>>>(Xb, Wqkv, QKV, 3072, 1024);
  attn_kernel<<<512, 256, 0, stream>>>(QKV, AO);
  gemm64<<<dim3(64, 8), 256, 0, stream>>>(AO, Wob, (float*)d_out, 1024, 1024);
}